// Round 12
// baseline (338.887 us; speedup 1.0000x reference)
//
#include <hip/hip_runtime.h>
#include <hip/hip_bf16.h>

// (B,N,D) = (4,4096,256) fp32 in/out.
//  proj3: fused q/k/v projection (3-term fp16-split MFMA), fp16 out,
//         q pre-scaled by log2e.  (verified R3-R11)
//  transpose_v: v -> vT[d][n]    (verified)
//  attn_flash7: 512 blocks x 256 thr (4 waves) -> 256-VGPR budget
//         (allocator budgets 2x native waves/SIMD: 8-wave blocks get 128 and
//         remat Q; 4-wave blocks get 256) AND 73KB LDS -> 2 blocks/CU =
//         2 waves/SIMD from INDEPENDENT blocks (no shared barrier).
//         Wave specialization: waves 0-1 producers (QK^T 32-key halves +
//         softmax + Pex), waves 2-3 consumers (merge + PV 128-col halves +
//         V reg prefetch + output). Depth-1 pipeline QK^T(t) || PV(t-1),
//         ONE __syncthreads per 64-key iter. K dbuf LDS via R9-verified
//         contiguous-source pre-swizzled DMA. Two complementary 32-row
//         passes (qtA, 127-qtA) -> every block ~65 equal iters.

#define SEQ   4096
#define DIM   256
#define LOG2E 1.4426950408889634f

typedef _Float16 f16;
typedef __attribute__((ext_vector_type(8)))  f16    f16x8;
typedef __attribute__((ext_vector_type(2)))  __fp16 pk16x2;
typedef __attribute__((ext_vector_type(16))) float  f32x16;

typedef const __attribute__((address_space(1))) unsigned int GAS;
typedef __attribute__((address_space(3)))       unsigned int LAS;
#define DMA16(g, l) __builtin_amdgcn_global_load_lds((GAS*)(g), (LAS*)(l), 16, 0, 0)

// ---------------------------------------------------------------------------
// Fused projection (verified). out = (X @ W^T + b) * scale, fp16.
// ---------------------------------------------------------------------------
__global__ __launch_bounds__(256) void proj3(
    const float* __restrict__ X,
    const float* __restrict__ Wq, const float* __restrict__ bq,
    const float* __restrict__ Wk, const float* __restrict__ bk,
    const float* __restrict__ Wv, const float* __restrict__ bv,
    f16* __restrict__ outq, f16* __restrict__ outk, f16* __restrict__ outv)
{
    const float* W; const float* bias; f16* out; float scale;
    if (blockIdx.y == 0)      { W = Wq; bias = bq; out = outq; scale = LOG2E; }
    else if (blockIdx.y == 1) { W = Wk; bias = bk; out = outk; scale = 1.f; }
    else                      { W = Wv; bias = bv; out = outv; scale = 1.f; }

    const int w = threadIdx.x >> 6, lane = threadIdx.x & 63;
    const int col = lane & 31, hi = lane >> 5;
    const int m0 = blockIdx.x * 64 + (w & 1) * 32;
    const int e0 = (w >> 1) * 128;

    f32x16 acc[4] = {};
    for (int s = 0; s < 16; ++s) {
        const float* xp = X + (size_t)(m0 + col) * DIM + s * 16 + 8 * hi;
        float xv[8];
        *(float4*)&xv[0] = *(const float4*)xp;
        *(float4*)&xv[4] = *(const float4*)(xp + 4);
        f16x8 xh, xl;
        #pragma unroll
        for (int i = 0; i < 8; ++i) {
            xh[i] = (f16)xv[i];
            xl[i] = (f16)(xv[i] - (float)xh[i]);
        }
        #pragma unroll
        for (int c = 0; c < 4; ++c) {
            const float* wp = W + (size_t)(e0 + c * 32 + col) * DIM + s * 16 + 8 * hi;
            float wv[8];
            *(float4*)&wv[0] = *(const float4*)wp;
            *(float4*)&wv[4] = *(const float4*)(wp + 4);
            f16x8 wh, wl;
            #pragma unroll
            for (int i = 0; i < 8; ++i) {
                wh[i] = (f16)wv[i];
                wl[i] = (f16)(wv[i] - (float)wh[i]);
            }
            acc[c] = __builtin_amdgcn_mfma_f32_32x32x16_f16(xh, wh, acc[c], 0, 0, 0);
            acc[c] = __builtin_amdgcn_mfma_f32_32x32x16_f16(xl, wh, acc[c], 0, 0, 0);
            acc[c] = __builtin_amdgcn_mfma_f32_32x32x16_f16(xh, wl, acc[c], 0, 0, 0);
        }
    }
    #pragma unroll
    for (int c = 0; c < 4; ++c) {
        const int e = e0 + c * 32 + col;
        const float b = bias[e];
        #pragma unroll
        for (int r = 0; r < 16; ++r) {
            const int m = m0 + (r & 3) + 8 * (r >> 2) + 4 * hi;
            out[(size_t)m * DIM + e] = (f16)((acc[c][r] + b) * scale);
        }
    }
}

// ---------------------------------------------------------------------------
// v (fp16 [N][256] per batch) -> vT (fp16 [256][N] per batch)  (verified)
// ---------------------------------------------------------------------------
__global__ void transpose_v(const f16* __restrict__ v, f16* __restrict__ vT)
{
    __shared__ f16 tile[32][33];
    const size_t pp = (size_t)SEQ * DIM;
    const f16* vb = v + blockIdx.z * pp;
    f16* vTb = vT + blockIdx.z * pp;
    const int n0 = blockIdx.x * 32, e0 = blockIdx.y * 32;
    #pragma unroll
    for (int r = 0; r < 4; ++r)
        tile[threadIdx.y + 8 * r][threadIdx.x] =
            vb[(size_t)(n0 + threadIdx.y + 8 * r) * DIM + e0 + threadIdx.x];
    __syncthreads();
    #pragma unroll
    for (int r = 0; r < 4; ++r)
        vTb[(size_t)(e0 + threadIdx.y + 8 * r) * SEQ + n0 + threadIdx.x] =
            tile[threadIdx.x][threadIdx.y + 8 * r];
}

// ---------------------------------------------------------------------------
// attn_flash7. K LDS per buffer (uint4 units, 2048 = 32KB, 64 keys):
//   [64 keys][32 chunks], idx = key*32 + (chunk ^ (key&7))   (verified R9)
// DMA instr m (0..31) = contiguous 1KB span, rows {2m,2m+1}; wave w issues
// m = 8w..8w+7 (all 4 waves participate).
// ---------------------------------------------------------------------------
__global__ __launch_bounds__(256, 1) void attn_flash7(
    const f16* __restrict__ qh, const f16* __restrict__ kh,
    const f16* __restrict__ vT, float* __restrict__ out, int nb)
{
    __shared__ uint4 kbuf[2][2048];      // 2 x 32KB K tiles (64 keys)
    __shared__ uint4 Pex[2][256];        // dbuf A-frags, (s*2+hi)*32+col, 8KB
    __shared__ float mlbuf[2][2][2][32]; // [buf][m|l][kq][q], 1KB

    int qtA, b;
    if (nb == 4) {
        const int lin = blockIdx.x;       // 512 blocks
        const int x = lin & 7;            // XCD
        b = x >> 1;                       // 2 XCDs per batch
        qtA = (x & 1) * 64 + (lin >> 3);  // [0,128): 32-row tile
    } else { qtA = blockIdx.x; b = 0; }   // grid 128

    const size_t pp = (size_t)SEQ * DIM;
    const f16* qhb = qh + b * pp;
    const char* kbyte = (const char*)(kh + b * pp);   // [4096][512B]
    const f16* vTb = vT + b * pp;                     // [256][4096]
    float* outb = out + b * pp;

    const int wid = threadIdx.x >> 6, lane = threadIdx.x & 63;
    const int col = lane & 31, hi = lane >> 5;
    const bool prod = (wid < 2);
    const int kq = wid & 1;               // producer: key half / consumer: col half
    const int e7 = col & 7;

    // loop-invariant K-DMA per-lane source offsets (verified R9)
    int kloff[4];
    #pragma unroll
    for (int jj = 0; jj < 4; ++jj)
        kloff[jj] = hi * 512 + (col ^ ((2 * jj + hi) & 7)) * 16;

    #define STAGE(buf, key0)                                                   \
        do {                                                                   \
            const char* kp = kbyte + (size_t)(key0) * 512;                     \
            _Pragma("unroll")                                                  \
            for (int i = 0; i < 8; ++i) {                                      \
                const int m = 8 * wid + i;                                     \
                DMA16(kp + m * 1024 + kloff[m & 3], &kbuf[buf][m * 64]);       \
            }                                                                  \
        } while (0)

    for (int pass = 0; pass < 2; ++pass) {
        const int qt = pass ? (127 - qtA) : qtA;
        const int q0 = qt * 32;
        const int nt = (qt + 2) >> 1;     // 64-key tiles

        // producers: Q fragments resident (single fp16, 64 VGPRs)
        f16x8 qhf[16];
        if (prod) {
            #pragma unroll
            for (int sl = 0; sl < 16; ++sl)
                qhf[sl] = *(const f16x8*)(qhb + (size_t)(q0 + col) * DIM + sl * 16 + 8 * hi);
        }

        STAGE(0, 0);
        __syncthreads();                  // drains DMA for tile 0

        float m_run = -1e28f, l_run = 0.f;
        f32x16 oacc[4] = {};              // consumer: cols 128*kq + 32*cg + col
        f16x8 vf[4][4];                   // consumer: V(t) regs [cg][s4]

        for (int t = 0; t < nt; ++t) {
            const int buf = t & 1;

            // ---- issue K DMA for tile t+1 (drained at this iter's barrier) ----
            if (t + 1 < nt) STAGE(buf ^ 1, 64 * (t + 1));

            if (prod) {
                // ---- QK^T: own 32-key half of tile t (verified R10 code) ----
                const int krow = (32 * kq + col) * 32;
                f32x16 s1 = {}, s2 = {};
                #pragma unroll
                for (int sl = 0; sl < 16; ++sl) {
                    const f16x8 kf = __builtin_bit_cast(f16x8,
                        kbuf[buf][krow + ((2 * sl + hi) ^ e7)]);
                    if (sl & 1) s2 = __builtin_amdgcn_mfma_f32_32x32x16_f16(kf, qhf[sl], s2, 0, 0, 0);
                    else        s1 = __builtin_amdgcn_mfma_f32_32x32x16_f16(kf, qhf[sl], s1, 0, 0, 0);
                }
                // ---- mask + wave-local softmax (verified) ----
                float sv[16];
                float pmax = -1e30f, tsum = 0.f;
                #pragma unroll
                for (int r = 0; r < 16; ++r) {
                    const int kg = 64 * t + 32 * kq + (r & 3) + 8 * (r >> 2) + 4 * hi;
                    const float x = (kg <= q0 + col) ? (s1[r] + s2[r]) : -1e30f;
                    sv[r] = x;
                    pmax = fmaxf(pmax, x);
                }
                pmax = fmaxf(pmax, __shfl_xor(pmax, 32));
                pmax = fmaxf(pmax, -1e28f);   // fully-masked half -> p = 0
                float p[16];
                #pragma unroll
                for (int r = 0; r < 16; ++r) {
                    p[r] = exp2f(sv[r] - pmax);
                    tsum += p[r];
                }
                tsum += __shfl_xor(tsum, 32);
                // A-frag build (verified cvt_pk + shfl_xor(32))
                uint32_t Wd[8], Od[8];
                #pragma unroll
                for (int jj = 0; jj < 8; ++jj)
                    Wd[jj] = __builtin_bit_cast(uint32_t,
                        __builtin_amdgcn_cvt_pkrtz(p[2 * jj], p[2 * jj + 1]));
                #pragma unroll
                for (int jj = 0; jj < 8; ++jj)
                    Od[jj] = (uint32_t)__shfl_xor((int)Wd[jj], 32);
                uint4 A0, A1;
                if (hi == 0) {
                    A0.x = Wd[0]; A0.y = Wd[1]; A0.z = Od[0]; A0.w = Od[1];
                    A1.x = Wd[4]; A1.y = Wd[5]; A1.z = Od[4]; A1.w = Od[5];
                } else {
                    A0.x = Od[2]; A0.y = Od[3]; A0.z = Wd[2]; A0.w = Wd[3];
                    A1.x = Od[6]; A1.y = Od[7]; A1.z = Wd[6]; A1.w = Wd[7];
                }
                Pex[buf][((2 * kq + 0) * 2 + hi) * 32 + col] = A0;  // keys [32kq,+16)
                Pex[buf][((2 * kq + 1) * 2 + hi) * 32 + col] = A1;  // keys [32kq+16,+16)
                if (lane < 32) {
                    mlbuf[buf][0][kq][col] = pmax;
                    mlbuf[buf][1][kq][col] = tsum;
                }
            } else {
                if (t > 0) {
                    // ---- merge m/l for tile t-1, defer-max rescale (verified) ----
                    const int bm = buf ^ 1;
                    const float mw0 = mlbuf[bm][0][0][col], mw1 = mlbuf[bm][0][1][col];
                    const float tw0 = mlbuf[bm][1][0][col], tw1 = mlbuf[bm][1][1][col];
                    const float mt = fmaxf(mw0, mw1);
                    float scale = 1.f;
                    if (__any(mt > m_run + 11.5415603f)) {   // 8-nat window (log2)
                        const float m_new = fmaxf(m_run, mt);
                        scale = exp2f(m_run - m_new);
                        m_run = m_new;
                        #pragma unroll
                        for (int r = 0; r < 16; ++r) {
                            const int qr = (r & 3) + 8 * (r >> 2) + 4 * hi;
                            const float scr = __shfl(scale, qr | (lane & 32));
                            oacc[0][r] *= scr; oacc[1][r] *= scr;
                            oacc[2][r] *= scr; oacc[3][r] *= scr;
                        }
                    }
                    const float c0 = exp2f(mw0 - m_run);
                    const float c1 = exp2f(mw1 - m_run);
                    l_run = l_run * scale + tw0 * c0 + tw1 * c1;
                    const f16 ch[2] = {(f16)c0, (f16)c1};
                    // ---- PV(t-1): own 128-col half, V regs from iter t-1 ----
                    #pragma unroll
                    for (int s4 = 0; s4 < 4; ++s4) {
                        f16x8 af = __builtin_bit_cast(f16x8, Pex[bm][(s4 * 2 + hi) * 32 + col]);
                        af = af * ch[s4 >> 1];
                        #pragma unroll
                        for (int cg = 0; cg < 4; ++cg)
                            oacc[cg] = __builtin_amdgcn_mfma_f32_32x32x16_f16(af, vf[cg][s4], oacc[cg], 0, 0, 0);
                    }
                }
                // ---- load V(t) regs (consumed next iter / epilogue) ----
                #pragma unroll
                for (int cg = 0; cg < 4; ++cg) {
                    const f16* vp = vTb + (size_t)(128 * kq + 32 * cg + col) * SEQ + 64 * t + 8 * hi;
                    #pragma unroll
                    for (int s4 = 0; s4 < 4; ++s4)
                        vf[cg][s4] = *(const f16x8*)(vp + 16 * s4);
                }
            }
            __syncthreads();   // drains this iter's DMA; publishes Pex/mlbuf
        }

        // ---- epilogue: consumers finish tile nt-1 and store ----
        if (!prod) {
            const int bm = (nt - 1) & 1;
            const float mw0 = mlbuf[bm][0][0][col], mw1 = mlbuf[bm][0][1][col];
            const float tw0 = mlbuf[bm][1][0][col], tw1 = mlbuf[bm][1][1][col];
            const float mt = fmaxf(mw0, mw1);
            float scale = 1.f;
            if (__any(mt > m_run + 11.5415603f)) {
                const float m_new = fmaxf(m_run, mt);
                scale = exp2f(m_run - m_new);
                m_run = m_new;
                #pragma unroll
                for (int r = 0; r < 16; ++r) {
                    const int qr = (r & 3) + 8 * (r >> 2) + 4 * hi;
                    const float scr = __shfl(scale, qr | (lane & 32));
                    oacc[0][r] *= scr; oacc[1][r] *= scr;
                    oacc[2][r] *= scr; oacc[3][r] *= scr;
                }
            }
            const float c0 = exp2f(mw0 - m_run);
            const float c1 = exp2f(mw1 - m_run);
            l_run = l_run * scale + tw0 * c0 + tw1 * c1;
            const f16 ch[2] = {(f16)c0, (f16)c1};
            #pragma unroll
            for (int s4 = 0; s4 < 4; ++s4) {
                f16x8 af = __builtin_bit_cast(f16x8, Pex[bm][(s4 * 2 + hi) * 32 + col]);
                af = af * ch[s4 >> 1];
                #pragma unroll
                for (int cg = 0; cg < 4; ++cg)
                    oacc[cg] = __builtin_amdgcn_mfma_f32_32x32x16_f16(af, vf[cg][s4], oacc[cg], 0, 0, 0);
            }
            const float linv = 1.f / l_run;
            #pragma unroll
            for (int r = 0; r < 16; ++r) {
                const int qr = (r & 3) + 8 * (r >> 2) + 4 * hi;
                const float lr = __shfl(linv, qr | (lane & 32));
                const int n = q0 + qr;
                #pragma unroll
                for (int cg = 0; cg < 4; ++cg)
                    outb[(size_t)n * DIM + 128 * kq + 32 * cg + col] = oacc[cg][r] * lr;
            }
        }
        __syncthreads();       // LDS + DMA quiesced before next pass
    }
    #undef STAGE
}

// ---------------------------------------------------------------------------
extern "C" void kernel_launch(void* const* d_in, const int* in_sizes, int n_in,
                              void* d_out, int out_size, void* d_ws, size_t ws_size,
                              hipStream_t stream) {
    const float* x  = (const float*)d_in[0];
    const float* Wq = (const float*)d_in[1];
    const float* bq = (const float*)d_in[2];
    const float* Wk = (const float*)d_in[3];
    const float* bk = (const float*)d_in[4];
    const float* Wv = (const float*)d_in[5];
    const float* bv = (const float*)d_in[6];
    float* out = (float*)d_out;

    const size_t PP = (size_t)SEQ * DIM;
    const size_t FULL = 4 * PP;

    if (ws_size >= FULL * 2 * 4) {
        f16* qh = (f16*)d_ws;
        f16* kh = qh + FULL;
        f16* vv = kh + FULL;
        f16* vT = vv + FULL;
        proj3<<<dim3(256, 3), 256, 0, stream>>>(x, Wq, bq, Wk, bk, Wv, bv, qh, kh, vv);
        transpose_v<<<dim3(128, 8, 4), dim3(32, 8), 0, stream>>>(vv, vT);
        attn_flash7<<<dim3(512), 256, 0, stream>>>(qh, kh, vT, out, 4);
    } else {
        f16* qh = (f16*)d_ws;
        f16* kh = qh + PP;
        f16* vv = kh + PP;
        f16* vT = vv + PP;
        for (int b = 0; b < 4; ++b) {
            const float* xb = x + b * PP;
            proj3<<<dim3(64, 3), 256, 0, stream>>>(xb, Wq, bq, Wk, bk, Wv, bv, qh, kh, vv);
            transpose_v<<<dim3(128, 8, 1), dim3(32, 8), 0, stream>>>(vv, vT);
            attn_flash7<<<dim3(128), 256, 0, stream>>>(qh, kh, vT, out + b * PP, 1);
        }
    }
}

// Round 13
// 245.820 us; speedup vs baseline: 1.3786x; 1.3786x over previous
//
#include <hip/hip_runtime.h>
#include <hip/hip_bf16.h>

// (B,N,D) = (4,4096,256) fp32 in/out.
//  proj3: fused q/k/v projection (3-term fp16-split MFMA), fp16 out,
//         q pre-scaled by log2e.  (verified R3-R12)
//  transpose_v: v -> vT[d][n]    (verified)
//  attn_flash8 = R11 engine + fixes:
//    - 256 blocks x 8 waves (512 thr), 64 q-rows = 2 subs x 4 kq-waves,
//      128-key K tiles in LDS (R9-verified contiguous-source preswizzled DMA).
//    - Q fragments in LDS (32KB, shared per sub) -> register demand ~100
//      fits the 8-wave 128-VGPR budget -> no Q remat (R11's defect).
//    - complementary passes (group jA then 63-jA) -> every block ~34 equal
//      iters, no causal tail (R12's verified balance).
//    - K single-buffered (LDS 114KB total): STAGE(t+1) issued AFTER bar1
//      (all QK^T reads of tile t complete block-wide), drained at iter-end
//      __syncthreads, hidden under merge+PV.

#define SEQ   4096
#define DIM   256
#define LOG2E 1.4426950408889634f

typedef _Float16 f16;
typedef __attribute__((ext_vector_type(8)))  f16    f16x8;
typedef __attribute__((ext_vector_type(16))) float  f32x16;

typedef const __attribute__((address_space(1))) unsigned int GAS;
typedef __attribute__((address_space(3)))       unsigned int LAS;
#define DMA16(g, l) __builtin_amdgcn_global_load_lds((GAS*)(g), (LAS*)(l), 16, 0, 0)

// ---------------------------------------------------------------------------
// Fused projection (verified). out = (X @ W^T + b) * scale, fp16.
// ---------------------------------------------------------------------------
__global__ __launch_bounds__(256) void proj3(
    const float* __restrict__ X,
    const float* __restrict__ Wq, const float* __restrict__ bq,
    const float* __restrict__ Wk, const float* __restrict__ bk,
    const float* __restrict__ Wv, const float* __restrict__ bv,
    f16* __restrict__ outq, f16* __restrict__ outk, f16* __restrict__ outv)
{
    const float* W; const float* bias; f16* out; float scale;
    if (blockIdx.y == 0)      { W = Wq; bias = bq; out = outq; scale = LOG2E; }
    else if (blockIdx.y == 1) { W = Wk; bias = bk; out = outk; scale = 1.f; }
    else                      { W = Wv; bias = bv; out = outv; scale = 1.f; }

    const int w = threadIdx.x >> 6, lane = threadIdx.x & 63;
    const int col = lane & 31, hi = lane >> 5;
    const int m0 = blockIdx.x * 64 + (w & 1) * 32;
    const int e0 = (w >> 1) * 128;

    f32x16 acc[4] = {};
    for (int s = 0; s < 16; ++s) {
        const float* xp = X + (size_t)(m0 + col) * DIM + s * 16 + 8 * hi;
        float xv[8];
        *(float4*)&xv[0] = *(const float4*)xp;
        *(float4*)&xv[4] = *(const float4*)(xp + 4);
        f16x8 xh, xl;
        #pragma unroll
        for (int i = 0; i < 8; ++i) {
            xh[i] = (f16)xv[i];
            xl[i] = (f16)(xv[i] - (float)xh[i]);
        }
        #pragma unroll
        for (int c = 0; c < 4; ++c) {
            const float* wp = W + (size_t)(e0 + c * 32 + col) * DIM + s * 16 + 8 * hi;
            float wv[8];
            *(float4*)&wv[0] = *(const float4*)wp;
            *(float4*)&wv[4] = *(const float4*)(wp + 4);
            f16x8 wh, wl;
            #pragma unroll
            for (int i = 0; i < 8; ++i) {
                wh[i] = (f16)wv[i];
                wl[i] = (f16)(wv[i] - (float)wh[i]);
            }
            acc[c] = __builtin_amdgcn_mfma_f32_32x32x16_f16(xh, wh, acc[c], 0, 0, 0);
            acc[c] = __builtin_amdgcn_mfma_f32_32x32x16_f16(xl, wh, acc[c], 0, 0, 0);
            acc[c] = __builtin_amdgcn_mfma_f32_32x32x16_f16(xh, wl, acc[c], 0, 0, 0);
        }
    }
    #pragma unroll
    for (int c = 0; c < 4; ++c) {
        const int e = e0 + c * 32 + col;
        const float b = bias[e];
        #pragma unroll
        for (int r = 0; r < 16; ++r) {
            const int m = m0 + (r & 3) + 8 * (r >> 2) + 4 * hi;
            out[(size_t)m * DIM + e] = (f16)((acc[c][r] + b) * scale);
        }
    }
}

// ---------------------------------------------------------------------------
// v (fp16 [N][256] per batch) -> vT (fp16 [256][N] per batch)  (verified)
// ---------------------------------------------------------------------------
__global__ void transpose_v(const f16* __restrict__ v, f16* __restrict__ vT)
{
    __shared__ f16 tile[32][33];
    const size_t pp = (size_t)SEQ * DIM;
    const f16* vb = v + blockIdx.z * pp;
    f16* vTb = vT + blockIdx.z * pp;
    const int n0 = blockIdx.x * 32, e0 = blockIdx.y * 32;
    #pragma unroll
    for (int r = 0; r < 4; ++r)
        tile[threadIdx.y + 8 * r][threadIdx.x] =
            vb[(size_t)(n0 + threadIdx.y + 8 * r) * DIM + e0 + threadIdx.x];
    __syncthreads();
    #pragma unroll
    for (int r = 0; r < 4; ++r)
        vTb[(size_t)(e0 + threadIdx.y + 8 * r) * SEQ + n0 + threadIdx.x] =
            tile[threadIdx.x][threadIdx.y + 8 * r];
}

// ---------------------------------------------------------------------------
// attn_flash8. K LDS (single buffer, 4096 uint4 = 64KB, 128 keys):
//   [128 keys][32 chunks], idx = key*32 + (chunk ^ (key&7))   (verified R9)
// Q LDS: per sub 1024 uint4, entry (sl*2+hi)*32+col  (fragment layout).
// DMA instr m (0..63) = contiguous 1KB span, rows {2m,2m+1}; wave w issues
// m = 8w..8w+7.
// ---------------------------------------------------------------------------
__global__ __launch_bounds__(512, 1) void attn_flash8(
    const f16* __restrict__ qh, const f16* __restrict__ kh,
    const f16* __restrict__ vT, float* __restrict__ out, int nb)
{
    __shared__ uint4 kbuf[4096];         // 64 KB: one 128-key K tile
    __shared__ uint4 Qlds[2048];         // 32 KB: 64 q-rows as frags (2 subs)
    __shared__ uint4 Pex[2][512];        // per-sub A-frags, 16 KB
    __shared__ float mlbuf[2][2][4][32]; // [sub][m|l][kq][q], 2 KB

    int jA, b;
    if (nb == 4) {
        const int lin = blockIdx.x;       // 256 blocks
        const int x = lin & 7;            // XCD
        b = x >> 1;                       // 2 XCDs per batch
        jA = (x & 1) * 32 + (lin >> 3);   // [0,64): 64-row group
    } else { jA = blockIdx.x; b = 0; }    // grid 64

    const size_t pp = (size_t)SEQ * DIM;
    const f16* qhb = qh + b * pp;
    const char* kbyte = (const char*)(kh + b * pp);   // [4096][512B]
    const f16* vTb = vT + b * pp;                     // [256][4096]
    float* outb = out + b * pp;

    const int wid = threadIdx.x >> 6, lane = threadIdx.x & 63;
    const int col = lane & 31, hi = lane >> 5;
    const int sub = wid >> 2;             // 32-row sub-block (0,1)
    const int kq = wid & 3;               // 32-key quarter / 64-col quarter
    const int e7 = col & 7;

    // loop-invariant K-DMA per-lane source offsets (verified R9)
    int kloff[4];
    #pragma unroll
    for (int jj = 0; jj < 4; ++jj)
        kloff[jj] = hi * 512 + (col ^ ((2 * jj + hi) & 7)) * 16;

    #define STAGE(key0)                                                        \
        do {                                                                   \
            const char* kp = kbyte + (size_t)(key0) * 512;                     \
            _Pragma("unroll")                                                  \
            for (int i = 0; i < 8; ++i) {                                      \
                const int m = 8 * wid + i;                                     \
                DMA16(kp + m * 1024 + kloff[m & 3], &kbuf[m * 64]);            \
            }                                                                  \
        } while (0)

    const f16* vcol0 = vTb + (size_t)(64 * kq + col) * SEQ + 8 * hi;

    for (int pass = 0; pass < 2; ++pass) {
        const int j = pass ? (63 - jA) : jA;       // 64-row group
        const int q0w = 64 * j + 32 * sub;         // this wave's q-rows
        const int nt = (j + 2) >> 1;               // 128-key tiles

        // ---- fill Qlds for own sub (4 slices per wave), stage tile 0 ----
        #pragma unroll
        for (int i = 0; i < 4; ++i) {
            const int sl = 4 * (wid & 3) + i;
            const f16x8 d = *(const f16x8*)(qhb + (size_t)(q0w + col) * DIM + sl * 16 + 8 * hi);
            Qlds[sub * 1024 + (sl * 2 + hi) * 32 + col] = __builtin_bit_cast(uint4, d);
        }
        STAGE(0);
        __syncthreads();                  // drains Q ds_writes + tile-0 DMA

        float m_run = -1e28f, l_run = 0.f;
        f32x16 oacc[2] = {};              // cols 64*kq + {col, 32+col}

        for (int t = 0; t < nt; ++t) {
            const int key0 = t << 7;

            // ---- QK^T: own 32-key quarter; K + Q frags from LDS ----
            const int krow = (32 * kq + col) * 32;
            const int qbase = sub * 1024;
            f32x16 s1 = {}, s2 = {};
            #pragma unroll
            for (int sl = 0; sl < 16; ++sl) {
                const f16x8 kf = __builtin_bit_cast(f16x8,
                    kbuf[krow + ((2 * sl + hi) ^ e7)]);
                const f16x8 qf = __builtin_bit_cast(f16x8,
                    Qlds[qbase + (sl * 2 + hi) * 32 + col]);
                if (sl & 1) s2 = __builtin_amdgcn_mfma_f32_32x32x16_f16(kf, qf, s2, 0, 0, 0);
                else        s1 = __builtin_amdgcn_mfma_f32_32x32x16_f16(kf, qf, s1, 0, 0, 0);
            }

            // ---- V prefetch A-half (slices 0..3, own 64-col quarter) ----
            f16x8 vfA[2][4];
            #pragma unroll
            for (int cg = 0; cg < 2; ++cg) {
                const f16* vp = vcol0 + (size_t)(32 * cg) * SEQ + key0;
                #pragma unroll
                for (int s = 0; s < 4; ++s) vfA[cg][s] = *(const f16x8*)(vp + 16 * s);
            }

            // ---- mask + wave-local softmax (verified R10/R11 verbatim) ----
            float sv[16];
            float pmax = -1e30f, tsum = 0.f;
            #pragma unroll
            for (int r = 0; r < 16; ++r) {
                const int kg = key0 + 32 * kq + (r & 3) + 8 * (r >> 2) + 4 * hi;
                const float x = (kg <= q0w + col) ? (s1[r] + s2[r]) : -1e30f;
                sv[r] = x;
                pmax = fmaxf(pmax, x);
            }
            pmax = fmaxf(pmax, __shfl_xor(pmax, 32));
            pmax = fmaxf(pmax, -1e28f);   // fully-masked quarter -> p = 0
            {
                float p[16];
                #pragma unroll
                for (int r = 0; r < 16; ++r) {
                    p[r] = exp2f(sv[r] - pmax);
                    tsum += p[r];
                }
                tsum += __shfl_xor(tsum, 32);
                // A-frag build (verified cvt_pk + shfl_xor(32))
                uint32_t Wd[8], Od[8];
                #pragma unroll
                for (int jj = 0; jj < 8; ++jj)
                    Wd[jj] = __builtin_bit_cast(uint32_t,
                        __builtin_amdgcn_cvt_pkrtz(p[2 * jj], p[2 * jj + 1]));
                #pragma unroll
                for (int jj = 0; jj < 8; ++jj)
                    Od[jj] = (uint32_t)__shfl_xor((int)Wd[jj], 32);
                uint4 A0, A1;
                if (hi == 0) {
                    A0.x = Wd[0]; A0.y = Wd[1]; A0.z = Od[0]; A0.w = Od[1];
                    A1.x = Wd[4]; A1.y = Wd[5]; A1.z = Od[4]; A1.w = Od[5];
                } else {
                    A0.x = Od[2]; A0.y = Od[3]; A0.z = Wd[2]; A0.w = Wd[3];
                    A1.x = Od[6]; A1.y = Od[7]; A1.z = Wd[6]; A1.w = Wd[7];
                }
                Pex[sub][((2 * kq + 0) * 2 + hi) * 32 + col] = A0;  // keys [32kq,+16)
                Pex[sub][((2 * kq + 1) * 2 + hi) * 32 + col] = A1;  // keys [32kq+16,+16)
            }
            if (lane < 32) {
                mlbuf[sub][0][kq][col] = pmax;
                mlbuf[sub][1][kq][col] = tsum;
            }
            // ---- bar1: DS-drain only (all K/Q LDS reads of tile t done) ----
            asm volatile("s_waitcnt lgkmcnt(0)" ::: "memory");
            __builtin_amdgcn_sched_barrier(0);
            __builtin_amdgcn_s_barrier();
            __builtin_amdgcn_sched_barrier(0);

            // ---- kbuf now reusable: issue DMA for tile t+1 ----
            if (t + 1 < nt) STAGE(key0 + 128);

            // ---- V prefetch B-half (slices 4..7) ----
            f16x8 vfB[2][4];
            #pragma unroll
            for (int cg = 0; cg < 2; ++cg) {
                const f16* vp = vcol0 + (size_t)(32 * cg) * SEQ + key0 + 64;
                #pragma unroll
                for (int s = 0; s < 4; ++s) vfB[cg][s] = *(const f16x8*)(vp + 16 * s);
            }

            // ---- 4-way m/l merge (verified), defer-max rescale ----
            const float mw0 = mlbuf[sub][0][0][col], mw1 = mlbuf[sub][0][1][col];
            const float mw2 = mlbuf[sub][0][2][col], mw3 = mlbuf[sub][0][3][col];
            const float tw0 = mlbuf[sub][1][0][col], tw1 = mlbuf[sub][1][1][col];
            const float tw2 = mlbuf[sub][1][2][col], tw3 = mlbuf[sub][1][3][col];
            const float mt = fmaxf(fmaxf(mw0, mw1), fmaxf(mw2, mw3));
            float scale = 1.f;
            if (__any(mt > m_run + 11.5415603f)) {   // 8-nat window (log2)
                const float m_new = fmaxf(m_run, mt);
                scale = exp2f(m_run - m_new);
                m_run = m_new;
                #pragma unroll
                for (int r = 0; r < 16; ++r) {
                    const int qr = (r & 3) + 8 * (r >> 2) + 4 * hi;
                    const float scr = __shfl(scale, qr | (lane & 32));
                    oacc[0][r] *= scr; oacc[1][r] *= scr;
                }
            }
            const float c0 = exp2f(mw0 - m_run), c1 = exp2f(mw1 - m_run);
            const float c2 = exp2f(mw2 - m_run), c3 = exp2f(mw3 - m_run);
            l_run = l_run * scale + tw0 * c0 + tw1 * c1 + tw2 * c2 + tw3 * c3;
            const f16 ch[4] = {(f16)c0, (f16)c1, (f16)c2, (f16)c3};

            // ---- PV: 8 slices x own 64-col quarter (V in regs) ----
            #pragma unroll
            for (int s4 = 0; s4 < 4; ++s4) {
                f16x8 af = __builtin_bit_cast(f16x8, Pex[sub][(s4 * 2 + hi) * 32 + col]);
                af = af * ch[s4 >> 1];
                oacc[0] = __builtin_amdgcn_mfma_f32_32x32x16_f16(af, vfA[0][s4], oacc[0], 0, 0, 0);
                oacc[1] = __builtin_amdgcn_mfma_f32_32x32x16_f16(af, vfA[1][s4], oacc[1], 0, 0, 0);
            }
            #pragma unroll
            for (int s4 = 0; s4 < 4; ++s4) {
                f16x8 af = __builtin_bit_cast(f16x8, Pex[sub][((s4 + 4) * 2 + hi) * 32 + col]);
                af = af * ch[2 + (s4 >> 1)];
                oacc[0] = __builtin_amdgcn_mfma_f32_32x32x16_f16(af, vfB[0][s4], oacc[0], 0, 0, 0);
                oacc[1] = __builtin_amdgcn_mfma_f32_32x32x16_f16(af, vfB[1][s4], oacc[1], 0, 0, 0);
            }

            __syncthreads();   // drains tile-t+1 DMA; orders Pex/mlbuf reuse
        }

        // ---- epilogue: divide by l, store fp32 ----
        const float linv = 1.f / l_run;
        #pragma unroll
        for (int r = 0; r < 16; ++r) {
            const int qr = (r & 3) + 8 * (r >> 2) + 4 * hi;
            const float lr = __shfl(linv, qr | (lane & 32));
            const int n = q0w + qr;
            outb[(size_t)n * DIM + 64 * kq + col]      = oacc[0][r] * lr;
            outb[(size_t)n * DIM + 64 * kq + 32 + col] = oacc[1][r] * lr;
        }
        __syncthreads();       // quiesce before next pass overwrites Qlds/kbuf
    }
    #undef STAGE
}

// ---------------------------------------------------------------------------
extern "C" void kernel_launch(void* const* d_in, const int* in_sizes, int n_in,
                              void* d_out, int out_size, void* d_ws, size_t ws_size,
                              hipStream_t stream) {
    const float* x  = (const float*)d_in[0];
    const float* Wq = (const float*)d_in[1];
    const float* bq = (const float*)d_in[2];
    const float* Wk = (const float*)d_in[3];
    const float* bk = (const float*)d_in[4];
    const float* Wv = (const float*)d_in[5];
    const float* bv = (const float*)d_in[6];
    float* out = (float*)d_out;

    const size_t PP = (size_t)SEQ * DIM;
    const size_t FULL = 4 * PP;

    if (ws_size >= FULL * 2 * 4) {
        f16* qh = (f16*)d_ws;
        f16* kh = qh + FULL;
        f16* vv = kh + FULL;
        f16* vT = vv + FULL;
        proj3<<<dim3(256, 3), 256, 0, stream>>>(x, Wq, bq, Wk, bk, Wv, bv, qh, kh, vv);
        transpose_v<<<dim3(128, 8, 4), dim3(32, 8), 0, stream>>>(vv, vT);
        attn_flash8<<<dim3(256), 512, 0, stream>>>(qh, kh, vT, out, 4);
    } else {
        f16* qh = (f16*)d_ws;
        f16* kh = qh + PP;
        f16* vv = kh + PP;
        f16* vT = vv + PP;
        for (int b = 0; b < 4; ++b) {
            const float* xb = x + b * PP;
            proj3<<<dim3(64, 3), 256, 0, stream>>>(xb, Wq, bq, Wk, bk, Wv, bv, qh, kh, vv);
            transpose_v<<<dim3(128, 8, 1), dim3(32, 8), 0, stream>>>(vv, vT);
            attn_flash8<<<dim3(64), 512, 0, stream>>>(qh, kh, vT, out + b * PP, 1);
        }
    }
}

// Round 14
// 173.572 us; speedup vs baseline: 1.9524x; 1.4162x over previous
//
#include <hip/hip_runtime.h>
#include <hip/hip_bf16.h>

// (B,N,D) = (4,4096,256) fp32 in/out.
//  proj3: fused q/k/v projection (3-term fp16-split MFMA), fp16 out,
//         q pre-scaled by log2e.  (verified R3-R13)
//  transpose_v: v -> vT[d][n]    (verified)
//  attn_flash9: THE config all 13 rounds point to:
//    - 512 blocks x 256 thr (4 waves) -> 244-VGPR budget (R12-proven):
//      qhf resident, no remat, no spill.
//    - 73KB LDS -> 2 INDEPENDENT blocks/CU -> 2 waves/SIMD with no shared
//      barrier: one block's DMA drain hides under the other's compute.
//    - all 4 waves compute (no R12 producer/consumer trap): 32 q-rows,
//      128-key K tile (single-buffered), wave kq owns a 32-key quarter
//      (R11 QK^T/softmax/Pex code verbatim), 4-way m/l merge, PV = own
//      64-col quarter over 8 slices, V reg-prefetched.
//    - STAGE(t+1) after bar1 (R13-verified safe), drained at iter-end sync.
//    - balance via co-residency: blocks lin and lin+256 share a CU;
//      f(k)=k<32?k:95-k makes the pair's iter counts sum ~33 on every CU.

#define SEQ   4096
#define DIM   256
#define LOG2E 1.4426950408889634f

typedef _Float16 f16;
typedef __attribute__((ext_vector_type(8)))  f16    f16x8;
typedef __attribute__((ext_vector_type(16))) float  f32x16;

typedef const __attribute__((address_space(1))) unsigned int GAS;
typedef __attribute__((address_space(3)))       unsigned int LAS;
#define DMA16(g, l) __builtin_amdgcn_global_load_lds((GAS*)(g), (LAS*)(l), 16, 0, 0)

// ---------------------------------------------------------------------------
// Fused projection (verified). out = (X @ W^T + b) * scale, fp16.
// ---------------------------------------------------------------------------
__global__ __launch_bounds__(256) void proj3(
    const float* __restrict__ X,
    const float* __restrict__ Wq, const float* __restrict__ bq,
    const float* __restrict__ Wk, const float* __restrict__ bk,
    const float* __restrict__ Wv, const float* __restrict__ bv,
    f16* __restrict__ outq, f16* __restrict__ outk, f16* __restrict__ outv)
{
    const float* W; const float* bias; f16* out; float scale;
    if (blockIdx.y == 0)      { W = Wq; bias = bq; out = outq; scale = LOG2E; }
    else if (blockIdx.y == 1) { W = Wk; bias = bk; out = outk; scale = 1.f; }
    else                      { W = Wv; bias = bv; out = outv; scale = 1.f; }

    const int w = threadIdx.x >> 6, lane = threadIdx.x & 63;
    const int col = lane & 31, hi = lane >> 5;
    const int m0 = blockIdx.x * 64 + (w & 1) * 32;
    const int e0 = (w >> 1) * 128;

    f32x16 acc[4] = {};
    for (int s = 0; s < 16; ++s) {
        const float* xp = X + (size_t)(m0 + col) * DIM + s * 16 + 8 * hi;
        float xv[8];
        *(float4*)&xv[0] = *(const float4*)xp;
        *(float4*)&xv[4] = *(const float4*)(xp + 4);
        f16x8 xh, xl;
        #pragma unroll
        for (int i = 0; i < 8; ++i) {
            xh[i] = (f16)xv[i];
            xl[i] = (f16)(xv[i] - (float)xh[i]);
        }
        #pragma unroll
        for (int c = 0; c < 4; ++c) {
            const float* wp = W + (size_t)(e0 + c * 32 + col) * DIM + s * 16 + 8 * hi;
            float wv[8];
            *(float4*)&wv[0] = *(const float4*)wp;
            *(float4*)&wv[4] = *(const float4*)(wp + 4);
            f16x8 wh, wl;
            #pragma unroll
            for (int i = 0; i < 8; ++i) {
                wh[i] = (f16)wv[i];
                wl[i] = (f16)(wv[i] - (float)wh[i]);
            }
            acc[c] = __builtin_amdgcn_mfma_f32_32x32x16_f16(xh, wh, acc[c], 0, 0, 0);
            acc[c] = __builtin_amdgcn_mfma_f32_32x32x16_f16(xl, wh, acc[c], 0, 0, 0);
            acc[c] = __builtin_amdgcn_mfma_f32_32x32x16_f16(xh, wl, acc[c], 0, 0, 0);
        }
    }
    #pragma unroll
    for (int c = 0; c < 4; ++c) {
        const int e = e0 + c * 32 + col;
        const float b = bias[e];
        #pragma unroll
        for (int r = 0; r < 16; ++r) {
            const int m = m0 + (r & 3) + 8 * (r >> 2) + 4 * hi;
            out[(size_t)m * DIM + e] = (f16)((acc[c][r] + b) * scale);
        }
    }
}

// ---------------------------------------------------------------------------
// v (fp16 [N][256] per batch) -> vT (fp16 [256][N] per batch)  (verified)
// ---------------------------------------------------------------------------
__global__ void transpose_v(const f16* __restrict__ v, f16* __restrict__ vT)
{
    __shared__ f16 tile[32][33];
    const size_t pp = (size_t)SEQ * DIM;
    const f16* vb = v + blockIdx.z * pp;
    f16* vTb = vT + blockIdx.z * pp;
    const int n0 = blockIdx.x * 32, e0 = blockIdx.y * 32;
    #pragma unroll
    for (int r = 0; r < 4; ++r)
        tile[threadIdx.y + 8 * r][threadIdx.x] =
            vb[(size_t)(n0 + threadIdx.y + 8 * r) * DIM + e0 + threadIdx.x];
    __syncthreads();
    #pragma unroll
    for (int r = 0; r < 4; ++r)
        vTb[(size_t)(e0 + threadIdx.y + 8 * r) * SEQ + n0 + threadIdx.x] =
            tile[threadIdx.x][threadIdx.y + 8 * r];
}

// ---------------------------------------------------------------------------
// attn_flash9. K LDS (single buffer, 4096 uint4 = 64KB, 128 keys):
//   [128 keys][32 chunks], idx = key*32 + (chunk ^ (key&7))   (verified R9)
// DMA instr m (0..63) = contiguous 1KB span, rows {2m,2m+1}; wave w issues
// m = 16w..16w+15.
// ---------------------------------------------------------------------------
__global__ __launch_bounds__(256, 1) void attn_flash9(
    const f16* __restrict__ qh, const f16* __restrict__ kh,
    const f16* __restrict__ vT, float* __restrict__ out, int nb)
{
    __shared__ uint4 kbuf[4096];         // 64 KB: one 128-key K tile
    __shared__ uint4 Pex[512];           // A-frags (slice*2+hi)*32+col, 8 KB
    __shared__ float mlbuf[2][4][32];    // [m|l][kq][q], 1 KB

    int qt, b;
    if (nb == 4) {
        const int lin = blockIdx.x;       // 512 blocks = 2/CU
        const int x = lin & 7;            // XCD
        b = x >> 1;                       // 2 XCDs per batch
        const int k = lin >> 3;           // dispatch slot [0,64); k and k+32
        const int f = (k < 32) ? k : (95 - k);   //   share a CU; f+f' = 63
        qt = 2 * f + (x & 1);             // [0,128): co-resident work ~const
    } else { qt = blockIdx.x; b = 0; }    // grid 128

    const size_t pp = (size_t)SEQ * DIM;
    const f16* qhb = qh + b * pp;
    const char* kbyte = (const char*)(kh + b * pp);   // [4096][512B]
    const f16* vTb = vT + b * pp;                     // [256][4096]
    float* outb = out + b * pp;

    const int wid = threadIdx.x >> 6, lane = threadIdx.x & 63;
    const int col = lane & 31, hi = lane >> 5;
    const int kq = wid;                   // 32-key quarter / 64-col quarter
    const int e7 = col & 7;
    const int q0 = qt * 32;
    const int nt = (qt + 4) >> 2;         // 128-key tiles

    // loop-invariant K-DMA per-lane source offsets (verified R9)
    int kloff[4];
    #pragma unroll
    for (int jj = 0; jj < 4; ++jj)
        kloff[jj] = hi * 512 + (col ^ ((2 * jj + hi) & 7)) * 16;

    #define STAGE(key0)                                                        \
        do {                                                                   \
            const char* kp = kbyte + (size_t)(key0) * 512;                     \
            _Pragma("unroll")                                                  \
            for (int i = 0; i < 16; ++i) {                                     \
                const int m = 16 * wid + i;                                    \
                DMA16(kp + m * 1024 + kloff[m & 3], &kbuf[m * 64]);            \
            }                                                                  \
        } while (0)

    // Q fragments resident (single fp16, 64 VGPRs; 244-reg budget holds them)
    f16x8 qhf[16];
    #pragma unroll
    for (int sl = 0; sl < 16; ++sl)
        qhf[sl] = *(const f16x8*)(qhb + (size_t)(q0 + col) * DIM + sl * 16 + 8 * hi);

    STAGE(0);
    __syncthreads();                      // drains tile-0 DMA

    float m_run = -1e28f, l_run = 0.f;
    f32x16 oacc[2] = {};                  // cols 64*kq + {col, 32+col}
    const f16* vcol0 = vTb + (size_t)(64 * kq + col) * SEQ + 8 * hi;

    for (int t = 0; t < nt; ++t) {
        const int key0 = t << 7;

        // ---- QK^T: own 32-key quarter, K frags from swizzled LDS ----
        const int krow = (32 * kq + col) * 32;
        f32x16 s1 = {}, s2 = {};
        #pragma unroll
        for (int sl = 0; sl < 16; ++sl) {
            const f16x8 kf = __builtin_bit_cast(f16x8,
                kbuf[krow + ((2 * sl + hi) ^ e7)]);
            if (sl & 1) s2 = __builtin_amdgcn_mfma_f32_32x32x16_f16(kf, qhf[sl], s2, 0, 0, 0);
            else        s1 = __builtin_amdgcn_mfma_f32_32x32x16_f16(kf, qhf[sl], s1, 0, 0, 0);
        }

        // ---- V prefetch A-half (slices 0..3, own 64-col quarter) ----
        f16x8 vfA[2][4];
        #pragma unroll
        for (int cg = 0; cg < 2; ++cg) {
            const f16* vp = vcol0 + (size_t)(32 * cg) * SEQ + key0;
            #pragma unroll
            for (int s = 0; s < 4; ++s) vfA[cg][s] = *(const f16x8*)(vp + 16 * s);
        }

        // ---- mask + wave-local softmax (verified R10/R11 verbatim) ----
        float sv[16];
        float pmax = -1e30f, tsum = 0.f;
        #pragma unroll
        for (int r = 0; r < 16; ++r) {
            const int kg = key0 + 32 * kq + (r & 3) + 8 * (r >> 2) + 4 * hi;
            const float x = (kg <= q0 + col) ? (s1[r] + s2[r]) : -1e30f;
            sv[r] = x;
            pmax = fmaxf(pmax, x);
        }
        pmax = fmaxf(pmax, __shfl_xor(pmax, 32));
        pmax = fmaxf(pmax, -1e28f);       // fully-masked quarter -> p = 0
        {
            float p[16];
            #pragma unroll
            for (int r = 0; r < 16; ++r) {
                p[r] = exp2f(sv[r] - pmax);
                tsum += p[r];
            }
            tsum += __shfl_xor(tsum, 32);
            // A-frag build (verified cvt_pk + shfl_xor(32))
            uint32_t Wd[8], Od[8];
            #pragma unroll
            for (int jj = 0; jj < 8; ++jj)
                Wd[jj] = __builtin_bit_cast(uint32_t,
                    __builtin_amdgcn_cvt_pkrtz(p[2 * jj], p[2 * jj + 1]));
            #pragma unroll
            for (int jj = 0; jj < 8; ++jj)
                Od[jj] = (uint32_t)__shfl_xor((int)Wd[jj], 32);
            uint4 A0, A1;
            if (hi == 0) {
                A0.x = Wd[0]; A0.y = Wd[1]; A0.z = Od[0]; A0.w = Od[1];
                A1.x = Wd[4]; A1.y = Wd[5]; A1.z = Od[4]; A1.w = Od[5];
            } else {
                A0.x = Od[2]; A0.y = Od[3]; A0.z = Wd[2]; A0.w = Wd[3];
                A1.x = Od[6]; A1.y = Od[7]; A1.z = Wd[6]; A1.w = Wd[7];
            }
            Pex[((2 * kq + 0) * 2 + hi) * 32 + col] = A0;  // keys [32kq,+16)
            Pex[((2 * kq + 1) * 2 + hi) * 32 + col] = A1;  // keys [32kq+16,+16)
        }
        if (lane < 32) {
            mlbuf[0][kq][col] = pmax;
            mlbuf[1][kq][col] = tsum;
        }
        // ---- bar1: DS-drain only (all kbuf reads of tile t complete) ----
        asm volatile("s_waitcnt lgkmcnt(0)" ::: "memory");
        __builtin_amdgcn_sched_barrier(0);
        __builtin_amdgcn_s_barrier();
        __builtin_amdgcn_sched_barrier(0);

        // ---- kbuf reusable: issue DMA for tile t+1 (drains at iter sync;
        //      co-resident block computes while we wait) ----
        if (t + 1 < nt) STAGE(key0 + 128);

        // ---- V prefetch B-half (slices 4..7) ----
        f16x8 vfB[2][4];
        #pragma unroll
        for (int cg = 0; cg < 2; ++cg) {
            const f16* vp = vcol0 + (size_t)(32 * cg) * SEQ + key0 + 64;
            #pragma unroll
            for (int s = 0; s < 4; ++s) vfB[cg][s] = *(const f16x8*)(vp + 16 * s);
        }

        // ---- 4-way m/l merge (verified), defer-max rescale ----
        const float mw0 = mlbuf[0][0][col], mw1 = mlbuf[0][1][col];
        const float mw2 = mlbuf[0][2][col], mw3 = mlbuf[0][3][col];
        const float tw0 = mlbuf[1][0][col], tw1 = mlbuf[1][1][col];
        const float tw2 = mlbuf[1][2][col], tw3 = mlbuf[1][3][col];
        const float mt = fmaxf(fmaxf(mw0, mw1), fmaxf(mw2, mw3));
        float scale = 1.f;
        if (__any(mt > m_run + 11.5415603f)) {   // 8-nat window (log2)
            const float m_new = fmaxf(m_run, mt);
            scale = exp2f(m_run - m_new);
            m_run = m_new;
            #pragma unroll
            for (int r = 0; r < 16; ++r) {
                const int qr = (r & 3) + 8 * (r >> 2) + 4 * hi;
                const float scr = __shfl(scale, qr | (lane & 32));
                oacc[0][r] *= scr; oacc[1][r] *= scr;
            }
        }
        const float c0 = exp2f(mw0 - m_run), c1 = exp2f(mw1 - m_run);
        const float c2 = exp2f(mw2 - m_run), c3 = exp2f(mw3 - m_run);
        l_run = l_run * scale + tw0 * c0 + tw1 * c1 + tw2 * c2 + tw3 * c3;
        const f16 ch[4] = {(f16)c0, (f16)c1, (f16)c2, (f16)c3};

        // ---- PV: 8 slices x own 64-col quarter (V in regs) ----
        #pragma unroll
        for (int s4 = 0; s4 < 4; ++s4) {
            f16x8 af = __builtin_bit_cast(f16x8, Pex[(s4 * 2 + hi) * 32 + col]);
            af = af * ch[s4 >> 1];
            oacc[0] = __builtin_amdgcn_mfma_f32_32x32x16_f16(af, vfA[0][s4], oacc[0], 0, 0, 0);
            oacc[1] = __builtin_amdgcn_mfma_f32_32x32x16_f16(af, vfA[1][s4], oacc[1], 0, 0, 0);
        }
        #pragma unroll
        for (int s4 = 0; s4 < 4; ++s4) {
            f16x8 af = __builtin_bit_cast(f16x8, Pex[((s4 + 4) * 2 + hi) * 32 + col]);
            af = af * ch[2 + (s4 >> 1)];
            oacc[0] = __builtin_amdgcn_mfma_f32_32x32x16_f16(af, vfB[0][s4], oacc[0], 0, 0, 0);
            oacc[1] = __builtin_amdgcn_mfma_f32_32x32x16_f16(af, vfB[1][s4], oacc[1], 0, 0, 0);
        }

        __syncthreads();   // drains tile-t+1 DMA; orders Pex/mlbuf reuse
    }

    // ---- epilogue: divide by l, store fp32 ----
    const float linv = 1.f / l_run;
    #pragma unroll
    for (int r = 0; r < 16; ++r) {
        const int qr = (r & 3) + 8 * (r >> 2) + 4 * hi;
        const float lr = __shfl(linv, qr | (lane & 32));
        const int n = q0 + qr;
        outb[(size_t)n * DIM + 64 * kq + col]      = oacc[0][r] * lr;
        outb[(size_t)n * DIM + 64 * kq + 32 + col] = oacc[1][r] * lr;
    }
    #undef STAGE
}

// ---------------------------------------------------------------------------
extern "C" void kernel_launch(void* const* d_in, const int* in_sizes, int n_in,
                              void* d_out, int out_size, void* d_ws, size_t ws_size,
                              hipStream_t stream) {
    const float* x  = (const float*)d_in[0];
    const float* Wq = (const float*)d_in[1];
    const float* bq = (const float*)d_in[2];
    const float* Wk = (const float*)d_in[3];
    const float* bk = (const float*)d_in[4];
    const float* Wv = (const float*)d_in[5];
    const float* bv = (const float*)d_in[6];
    float* out = (float*)d_out;

    const size_t PP = (size_t)SEQ * DIM;
    const size_t FULL = 4 * PP;

    if (ws_size >= FULL * 2 * 4) {
        f16* qh = (f16*)d_ws;
        f16* kh = qh + FULL;
        f16* vv = kh + FULL;
        f16* vT = vv + FULL;
        proj3<<<dim3(256, 3), 256, 0, stream>>>(x, Wq, bq, Wk, bk, Wv, bv, qh, kh, vv);
        transpose_v<<<dim3(128, 8, 4), dim3(32, 8), 0, stream>>>(vv, vT);
        attn_flash9<<<dim3(512), 256, 0, stream>>>(qh, kh, vT, out, 4);
    } else {
        f16* qh = (f16*)d_ws;
        f16* kh = qh + PP;
        f16* vv = kh + PP;
        f16* vT = vv + PP;
        for (int b = 0; b < 4; ++b) {
            const float* xb = x + b * PP;
            proj3<<<dim3(64, 3), 256, 0, stream>>>(xb, Wq, bq, Wk, bk, Wv, bv, qh, kh, vv);
            transpose_v<<<dim3(128, 8, 1), dim3(32, 8), 0, stream>>>(vv, vT);
            attn_flash9<<<dim3(128), 256, 0, stream>>>(qh, kh, vT, out + b * PP, 1);
        }
    }
}